// Round 5
// baseline (3279.497 us; speedup 1.0000x reference)
//
#include <hip/hip_runtime.h>
#include <math.h>

#define NUM_K 4096
#define DIM   256
#define TLEN  1024
#define DT    (DIM * TLEN)     // 262144, per-batch z stride
#define ZS    68               // LDS row stride (64 cols + 4 pad), keeps b128 align
#define KC    64               // codes per chunk

// ---------------- K1: wnorm = l2norm(weight), numpy-bitwise ----------------
// np.sum(x*x) pairwise scheme for n=256: two 128-blocks, each with 8 accumulator
// chains r[j] += fl(x[i+j]^2) (plain adds, NO FMA), combined
// ((r0+r1)+(r2+r3))+((r4+r5)+(r6+r7)); blocks added last. Then IEEE sqrt/max/div.
__global__ __launch_bounds__(256) void norm_weight_np_kernel(const float* __restrict__ w,
                                                             float* __restrict__ wnorm) {
  const int k = blockIdx.x * 256 + threadIdx.x;
  const float* row = w + (size_t)k * DIM;
  float p[2];
#pragma unroll
  for (int blk = 0; blk < 2; ++blk) {
    const float* b = row + blk * 128;
    float r[8];
#pragma unroll
    for (int j = 0; j < 8; ++j) r[j] = __fmul_rn(b[j], b[j]);
    for (int i = 8; i < 128; i += 8) {
#pragma unroll
      for (int j = 0; j < 8; ++j) r[j] = __fadd_rn(r[j], __fmul_rn(b[i + j], b[i + j]));
    }
    p[blk] = __fadd_rn(__fadd_rn(__fadd_rn(r[0], r[1]), __fadd_rn(r[2], r[3])),
                       __fadd_rn(__fadd_rn(r[4], r[5]), __fadd_rn(r[6], r[7])));
  }
  const float ss = __fadd_rn(p[0], p[1]);
  const float m  = fmaxf(__fsqrt_rn(ss), 1e-6f);
  // wnorm region is only 4B-aligned (odd float offset in d_out) -> scalar stores
  float* o = wnorm + (size_t)k * DIM;
  for (int d = 0; d < DIM; ++d) o[d] = __fdiv_rn(row[d], m);
}

// ---------------- K2: main fused kernel ----------------
// grid 1024: block = (batch bb, 64-token slab t0).
// Spec = the harness's NUMPY fp32 path (R1-R4 post-mortem):
//   zn = fl32(z / max(np_pairwise_sqrt_ss, eps))   [np.sum pairwise-8, no FMA]
//   cos[n,k] = single sequential FMA chain over d=0..255 (BLAS sgemm microkernel:
//              one accumulator per C element, one FMA per k-step, k ascending)
//   idx = argmax, first occurrence on ties.
// So the fp32 seq-FMA scan value IS the verdict — no fp64 refine.
__global__ __launch_bounds__(256) void vq_main_kernel(
    const float* __restrict__ z, const float* __restrict__ weight,
    const float* __restrict__ wnorm, float* __restrict__ out_q,
    float* __restrict__ out_codes, float* __restrict__ counts,
    float* __restrict__ dw, float* __restrict__ loss_accum) {
  __shared__ float zt[DIM * ZS];   // z tile [d][t]; raw, then normalized in place
  __shared__ float wt[DIM * ZS];   // code chunk [d][c]; reused as reduce scratch after loop
  __shared__ float tnorm[64];      // per-token m = max(||z||, 1e-6), np-bitwise
  __shared__ int   fidx[64];

  const int tid = threadIdx.x;
  const int bb  = blockIdx.x >> 4;
  const int t0  = (blockIdx.x & 15) << 6;
  const float* zbase = z + bb * DT + t0;

  // ---- stage z tile: [d][t] ----
  {
    const int dl = tid >> 4;             // 0..15
    const int tl = (tid & 15) << 2;      // 0..60
#pragma unroll 4
    for (int i = 0; i < 16; ++i) {
      const int d = (i << 4) + dl;
      const float4 v = *(const float4*)(zbase + d * TLEN + tl);
      *(float4*)(&zt[d * ZS + tl]) = v;
    }
  }
  __syncthreads();

  // ---- per-token norms, numpy-bitwise pairwise scheme ----
  if (tid < 64) {
    float p[2];
#pragma unroll
    for (int blk = 0; blk < 2; ++blk) {
      float r[8];
#pragma unroll
      for (int j = 0; j < 8; ++j) {
        const float v = zt[(blk * 128 + j) * ZS + tid];
        r[j] = __fmul_rn(v, v);
      }
      for (int i = 8; i < 128; i += 8) {
#pragma unroll
        for (int j = 0; j < 8; ++j) {
          const float v = zt[(blk * 128 + i + j) * ZS + tid];
          r[j] = __fadd_rn(r[j], __fmul_rn(v, v));
        }
      }
      p[blk] = __fadd_rn(__fadd_rn(__fadd_rn(r[0], r[1]), __fadd_rn(r[2], r[3])),
                         __fadd_rn(__fadd_rn(r[4], r[5]), __fadd_rn(r[6], r[7])));
    }
    const float ss = __fadd_rn(p[0], p[1]);
    tnorm[tid] = fmaxf(__fsqrt_rn(ss), 1e-6f);
  }
  __syncthreads();
  // ---- normalize z in place: zn = fl32(z / m), IEEE divide (np-bitwise) ----
  {
    const int t = tid & 63, q = tid >> 6;
    const float m = tnorm[t];
#pragma unroll 4
    for (int dd = 0; dd < 64; ++dd) {
      const int d = (q << 6) + dd;
      zt[d * ZS + t] = __fdiv_rn(zt[d * ZS + t], m);
    }
  }

  // ---- code-chunk loop: fp32 seq-FMA scan, streaming argmax (first-max ties) ----
  const int tt = tid & 15;   // token quad: tokens 4tt..4tt+3
  const int cc = tid >> 4;   // code quad within chunk: codes 4cc..4cc+3
  float v1[4] = {-INFINITY, -INFINITY, -INFINITY, -INFINITY};
  int   i1[4] = {0, 0, 0, 0};

  for (int chunk = 0; chunk < NUM_K / KC; ++chunk) {
    __syncthreads();  // previous chunk's readers done before overwrite
    // stage + transpose wnorm[chunk*64 .. +63][0..255] -> wt[d][c]
    {
      const float* wn = wnorm + chunk * KC * DIM;
#pragma unroll 4
      for (int i = 0; i < 16; ++i) {
        const int cb = i << 2;
        const float* p = wn + cb * DIM + tid;     // lanes -> consecutive d: coalesced
        const float a0 = p[0];
        const float a1 = p[DIM];
        const float a2 = p[2 * DIM];
        const float a3 = p[3 * DIM];
        *(float4*)(&wt[tid * ZS + cb]) = make_float4(a0, a1, a2, a3);
      }
    }
    __syncthreads();

    float acc[4][4] = {{0.f}};
#pragma unroll 4
    for (int d = 0; d < DIM; ++d) {          // single FMA chain per (token,code), d ascending
      const float4 a = *(const float4*)(&zt[d * ZS + (tt << 2)]);
      const float4 b = *(const float4*)(&wt[d * ZS + (cc << 2)]);
      const float af[4] = {a.x, a.y, a.z, a.w};
      const float bf[4] = {b.x, b.y, b.z, b.w};
#pragma unroll
      for (int ii = 0; ii < 4; ++ii)
#pragma unroll
        for (int jj = 0; jj < 4; ++jj)
          acc[ii][jj] = fmaf(af[ii], bf[jj], acc[ii][jj]);
    }

    // streaming argmax; ascending code order + strict '>' keeps first occurrence
#pragma unroll
    for (int jj = 0; jj < 4; ++jj) {
      const int c = (chunk << 6) + (cc << 2) + jj;
#pragma unroll
      for (int ii = 0; ii < 4; ++ii) {
        const float s = acc[ii][jj];
        if (c != 0 && s > v1[ii]) { v1[ii] = s; i1[ii] = c; }
      }
    }
  }

  // ---- cross-thread argmax reduce (reuse wt as scratch), lower index on ties ----
  __syncthreads();  // all compute reads of wt done
  float* rv1 = wt;                  // [16][64]
  int*   ri1 = (int*)(wt + 1024);   // [16][64]

#pragma unroll
  for (int ii = 0; ii < 4; ++ii) {
    const int tok = (tt << 2) + ii;
    rv1[cc * 64 + tok] = v1[ii];  ri1[cc * 64 + tok] = i1[ii];
  }
  __syncthreads();
  if (tid < 64) {
    float b1 = -INFINITY; int x1 = 0;
    for (int c = 0; c < 16; ++c) {
      const float v = rv1[c * 64 + tid];
      const int  ix = ri1[c * 64 + tid];
      if (v > b1 || (v == b1 && ix < x1)) { b1 = v; x1 = ix; }
    }
    fidx[tid] = x1;
    out_codes[bb * TLEN + t0 + tid] = (float)x1;
    atomicAdd(&counts[x1], 1.0f);
  }
  __syncthreads();

  // ---- output phase: quantized (= weight[idx]), loss, dw ----
  {
    const int wv = tid >> 6, lane = tid & 63;
    const int code = fidx[lane];
    const float m = tnorm[lane];
    const float* wrow = weight + code * DIM;
    float* qbase = out_q + bb * DT + t0 + lane;
    float* dwrow = dw + code * DIM;
    float lpart = 0.f;
#pragma unroll 4
    for (int dd = 0; dd < 64; ++dd) {
      const int d = (wv << 6) + dd;
      const float wval = wrow[d];                 // L2-hot gather
      const float zn   = zt[d * ZS + lane];       // normalized z (== flat_z_norm, np-bitwise)
      qbase[d * TLEN] = wval;                     // coalesced over lanes
      const float df = wval - zn * m;             // reconstruct raw z (~1e-7 err, ok for loss)
      lpart = fmaf(df, df, lpart);
      atomicAdd(&dwrow[d], zn);                   // dw = segment_sum(flat_z_norm)
    }
#pragma unroll
    for (int off = 32; off; off >>= 1) lpart += __shfl_down(lpart, off, 64);
    if (lane == 0) atomicAdd(loss_accum, lpart);
  }
}

// ---------------- K3: new_cs, n, loss scalar ----------------
__global__ __launch_bounds__(256) void finalize_cs_kernel(
    const float* __restrict__ counts, const float* __restrict__ ema_cs,
    float* __restrict__ out_ncs, float* __restrict__ ws_n,
    const float* __restrict__ loss_accum, float* __restrict__ out_loss) {
  __shared__ float red[4];
  const int tid = threadIdx.x;
  float part = 0.f;
  for (int k = tid; k < NUM_K; k += 256) {
    const float v = (k == 0) ? 0.f : 0.99f * ema_cs[k] + 0.01f * counts[k];
    out_ncs[k] = v;
    part += v;
  }
#pragma unroll
  for (int off = 32; off; off >>= 1) part += __shfl_down(part, off, 64);
  if ((tid & 63) == 0) red[tid >> 6] = part;
  __syncthreads();
  if (tid == 0) {
    ws_n[0] = red[0] + red[1] + red[2] + red[3];
    out_loss[0] = 0.25f * loss_accum[0] / 16777216.0f;  // mean over B*T*D
  }
}

// ---------------- K4: new_ema_w (in place over dw) + new_weight ----------------
__global__ __launch_bounds__(256) void finalize_w_kernel(
    const float* __restrict__ ema_w, const float* __restrict__ ncs,
    const float* __restrict__ ws_n, float* __restrict__ new_ema_w,
    float* __restrict__ new_weight) {
  const int wid  = threadIdx.x >> 6;
  const int lane = threadIdx.x & 63;
  const int k    = (blockIdx.x << 2) + wid;
  const float n  = ws_n[0];
  const float cs = (ncs[k] + 1e-5f) / (n + 4096.0f * 1e-5f) * n;
  const float* erow = ema_w + k * DIM;
  float* nrow = new_ema_w + k * DIM;
  float* wrow = new_weight + k * DIM;
  const int d0 = lane << 2;
  float u[4]; float ss = 0.f;
#pragma unroll
  for (int j = 0; j < 4; ++j) {
    const float dwv = nrow[d0 + j];
    const float val = (k == 0) ? 0.f : 0.99f * erow[d0 + j] + 0.01f * dwv;
    nrow[d0 + j] = val;
    const float uu = val / cs;
    u[j] = uu;
    ss = fmaf(uu, uu, ss);
  }
#pragma unroll
  for (int off = 32; off; off >>= 1) ss += __shfl_xor(ss, off, 64);
  const float m = fmaxf(sqrtf(ss), 1e-6f);
#pragma unroll
  for (int j = 0; j < 4; ++j) wrow[d0 + j] = u[j] / m;
}

extern "C" void kernel_launch(void* const* d_in, const int* in_sizes, int n_in,
                              void* d_out, int out_size, void* d_ws, size_t ws_size,
                              hipStream_t stream) {
  const float* z      = (const float*)d_in[0];   // [64,256,1024]
  const float* weight = (const float*)d_in[1];   // [4096,256]
  const float* ema_cs = (const float*)d_in[2];   // [4096]
  const float* ema_w  = (const float*)d_in[3];   // [4096,256]

  float* out = (float*)d_out;
  // output layout (floats): quantized | loss | codes | new_weight | new_cs | new_ema_w
  float* out_q     = out;                    // 16777216
  float* out_loss  = out + 16777216;         // 1
  float* out_codes = out + 16777217;         // 65536
  float* out_nw    = out + 16842753;         // 1048576 (also temp wnorm storage)
  float* out_ncs   = out + 17891329;         // 4096
  float* out_new   = out + 17895425;         // 1048576 (dw accumulates here, then in-place)

  float* counts     = (float*)d_ws;          // 4096 floats
  float* loss_accum = counts + 4096;         // 1
  float* ws_n       = counts + 4097;         // 1

  hipMemsetAsync(d_ws, 0, 4098 * sizeof(float), stream);
  hipMemsetAsync(out_new, 0, (size_t)NUM_K * DIM * sizeof(float), stream);

  norm_weight_np_kernel<<<NUM_K / 256, 256, 0, stream>>>(weight, out_nw);
  vq_main_kernel<<<1024, 256, 0, stream>>>(z, weight, out_nw, out_q, out_codes,
                                           counts, out_new, loss_accum);
  finalize_cs_kernel<<<1, 256, 0, stream>>>(counts, ema_cs, out_ncs, ws_n,
                                            loss_accum, out_loss);
  finalize_w_kernel<<<NUM_K / 4, 256, 0, stream>>>(ema_w, out_ncs, ws_n,
                                                   out_new, out_nw);
}